// Round 2
// baseline (77374.036 us; speedup 1.0000x reference)
//
#include <hip/hip_runtime.h>
#include <hip/hip_bf16.h>
#include <math.h>

// Problem constants
#define BATCH 4
#define CDIM 192
#define HDIM 224
#define WDIM 224
#define HWSZ (HDIM * WDIM)            // 50176
#define NWH 28                        // 224/8
#define NWIN (BATCH * NWH * NWH)      // 3136
#define TOK 64
#define MTOK (NWIN * TOK)             // 200704
#define HEADS 6
#define C3 (3 * CDIM)                 // 576
#define C4 (4 * CDIM)                 // 768
#define IMGSZ (BATCH * CDIM * HWSZ)   // 38535168
#define ATTN_SCALE 0.17677669529663687f
#define LN_EPS 1e-6f
#define GELU_K 0.70710678118654752f

// ---------------------------------------------------------------------------
// K1: 1x1 conv == per-batch GEMM: f1[b][o][p] = sum_c w1[o][c]*x[b][c][p] + b1[o]
__launch_bounds__(256)
__global__ void conv1x1_kernel(const float* __restrict__ x,
                               const float* __restrict__ w1,
                               const float* __restrict__ b1,
                               float* __restrict__ f1) {
    __shared__ __align__(16) float As[16][68];
    __shared__ __align__(16) float Bs[16][64];
    const int tid = threadIdx.x;
    const int p0 = blockIdx.x * 64;
    const int m0 = blockIdx.y * 64;
    const int b  = blockIdx.z;
    const int tm = tid >> 4, tn = tid & 15;
    const int mload = tid >> 2, kload = (tid & 3) * 4;
    const int kw = tid >> 4, nw = (tid & 15) * 4;
    float acc[4][4] = {};
    const float* xb = x + (size_t)b * CDIM * HWSZ;
    for (int k0 = 0; k0 < CDIM; k0 += 16) {
        float4 av = *(const float4*)&w1[(size_t)(m0 + mload) * CDIM + k0 + kload];
        float4 bv = *(const float4*)&xb[(size_t)(k0 + kw) * HWSZ + p0 + nw];
        __syncthreads();
        As[kload + 0][mload] = av.x;
        As[kload + 1][mload] = av.y;
        As[kload + 2][mload] = av.z;
        As[kload + 3][mload] = av.w;
        *(float4*)&Bs[kw][nw] = bv;
        __syncthreads();
#pragma unroll
        for (int kk = 0; kk < 16; ++kk) {
            float a[4], bb[4];
            *(float4*)a  = *(const float4*)&As[kk][tm * 4];
            *(float4*)bb = *(const float4*)&Bs[kk][tn * 4];
#pragma unroll
            for (int i = 0; i < 4; ++i)
#pragma unroll
                for (int j = 0; j < 4; ++j) acc[i][j] += a[i] * bb[j];
        }
    }
    float* outb = f1 + (size_t)b * CDIM * HWSZ;
#pragma unroll
    for (int i = 0; i < 4; ++i) {
        int m = m0 + tm * 4 + i;
        float bias = b1[m];
        float4 o = make_float4(acc[i][0] + bias, acc[i][1] + bias,
                               acc[i][2] + bias, acc[i][3] + bias);
        *(float4*)&outb[(size_t)m * HWSZ + p0 + tn * 4] = o;
    }
}

// ---------------------------------------------------------------------------
// K2: depthwise 3x3 SAME, NCHW, one thread per element.
__launch_bounds__(256)
__global__ void dwconv_kernel(const float* __restrict__ f1,
                              const float* __restrict__ w_dw,
                              const float* __restrict__ b_dw,
                              float* __restrict__ f2) {
    unsigned int idx = blockIdx.x * 256u + threadIdx.x;
    int w = idx % WDIM;
    unsigned int r = idx / WDIM;
    int h = r % HDIM;
    unsigned int bc = r / HDIM;
    int c = bc % CDIM;
    const float* base = f1 + (size_t)bc * HWSZ;
    const float* wd = w_dw + c * 9;
    float acc = b_dw[c];
#pragma unroll
    for (int ky = 0; ky < 3; ++ky) {
        int hy = h + ky - 1;
        if (hy < 0 || hy >= HDIM) continue;
#pragma unroll
        for (int kx = 0; kx < 3; ++kx) {
            int wx = w + kx - 1;
            if (wx < 0 || wx >= WDIM) continue;
            acc += base[hy * WDIM + wx] * wd[ky * 3 + kx];
        }
    }
    f2[idx] = acc;
}

// ---------------------------------------------------------------------------
// K3: LayerNorm over C + window partition -> token-major p[M][192].
__launch_bounds__(256)
__global__ void ln_part_kernel(const float* __restrict__ f2,
                               const float* __restrict__ ln_g,
                               const float* __restrict__ ln_b,
                               float* __restrict__ p) {
    __shared__ float T[CDIM][33];
    __shared__ float Rs[8][32], Rs2[8][32];
    __shared__ float Mu[32], Rsig[32];
    const int tid = threadIdx.x;
    const int wt = blockIdx.x, h = blockIdx.y, b = blockIdx.z;
    const int w0 = wt * 32;
    const size_t rowbase = (size_t)b * CDIM * HWSZ + (size_t)h * WDIM + w0;
    for (int idx = tid; idx < CDIM * 32; idx += 256) {
        int c = idx >> 5, j = idx & 31;
        T[c][j] = f2[rowbase + (size_t)c * HWSZ + j];
    }
    __syncthreads();
    {
        int j = tid & 31, q = tid >> 5;
        float s = 0.f, s2 = 0.f;
#pragma unroll
        for (int i = 0; i < 24; ++i) {
            float v = T[q * 24 + i][j];
            s += v; s2 += v * v;
        }
        Rs[q][j] = s; Rs2[q][j] = s2;
    }
    __syncthreads();
    if (tid < 32) {
        float s = 0.f, s2 = 0.f;
#pragma unroll
        for (int q = 0; q < 8; ++q) { s += Rs[q][tid]; s2 += Rs2[q][tid]; }
        float mu = s * (1.0f / CDIM);
        float var = s2 * (1.0f / CDIM) - mu * mu;
        Mu[tid] = mu;
        Rsig[tid] = rsqrtf(var + LN_EPS);
    }
    __syncthreads();
    const int l = tid & 63;
    const int jo = tid >> 6;
    for (int it = 0; it < 8; ++it) {
        int j = it * 4 + jo;
        int w = w0 + j;
        size_t token = ((size_t)(b * NWH + (h >> 3)) * NWH + (w >> 3)) * TOK
                       + ((h & 7) * 8 + (w & 7));
        float mu = Mu[j], rs = Rsig[j];
#pragma unroll
        for (int rep = 0; rep < 3; ++rep) {
            int c = l + rep * 64;
            p[token * CDIM + c] = (T[c][j] - mu) * rs * ln_g[c] + ln_b[c];
        }
    }
}

// ---------------------------------------------------------------------------
// K4: fused qkv + attention per (window, head). 256 threads.
// LDS: PT 64x196 (p tile, later overlaid by q/k/v/P), WS 16x100 (w stage).
__launch_bounds__(256)
__global__ void attn_fused_kernel(const float* __restrict__ p,
                                  const float* __restrict__ w_qkv,
                                  const float* __restrict__ b_qkv,
                                  float* __restrict__ oa) {
    __shared__ float PT[64 * 196];   // 50176 B
    __shared__ float WS[16 * 100];   // 6400 B
    const int tid = threadIdx.x;
    const int win = blockIdx.x, head = blockIdx.y;
    const size_t pbase = (size_t)win * TOK * CDIM;
    for (int i4 = tid * 4; i4 < 64 * 192; i4 += 1024) {
        float4 v = *(const float4*)&p[pbase + i4];
        int r = i4 / 192, c = i4 - r * 192;
        *(float4*)&PT[r * 196 + c] = v;
    }
    const int tr = tid >> 5, tc = tid & 31;
    float acc[8][3] = {};
    for (int k0 = 0; k0 < 192; k0 += 16) {
        __syncthreads();
        for (int idx = tid; idx < 16 * 96; idx += 256) {
            int kk = idx / 96, j = idx - kk * 96;
            int col = (j < 32) ? head * 32 + j
                    : (j < 64) ? 192 + head * 32 + (j - 32)
                               : 384 + head * 32 + (j - 64);
            WS[kk * 100 + j] = w_qkv[(size_t)(k0 + kk) * C3 + col];
        }
        __syncthreads();
#pragma unroll
        for (int k4 = 0; k4 < 16; k4 += 4) {
            float4 a[8];
#pragma unroll
            for (int i = 0; i < 8; ++i)
                a[i] = *(const float4*)&PT[(tr + 8 * i) * 196 + k0 + k4];
#pragma unroll
            for (int kk = 0; kk < 4; ++kk) {
                float b0 = WS[(k4 + kk) * 100 + tc];
                float b1 = WS[(k4 + kk) * 100 + tc + 32];
                float b2 = WS[(k4 + kk) * 100 + tc + 64];
#pragma unroll
                for (int i = 0; i < 8; ++i) {
                    float av = (kk == 0) ? a[i].x : (kk == 1) ? a[i].y
                             : (kk == 2) ? a[i].z : a[i].w;
                    acc[i][0] += av * b0;
                    acc[i][1] += av * b1;
                    acc[i][2] += av * b2;
                }
            }
        }
    }
    __syncthreads();   // all PT reads done; overlay q/k/v
    {
        float bq = b_qkv[head * 32 + tc];
        float bk = b_qkv[192 + head * 32 + tc];
        float bv = b_qkv[384 + head * 32 + tc];
#pragma unroll
        for (int i = 0; i < 8; ++i) {
            int r = tr + 8 * i;
            PT[r * 33 + tc]          = acc[i][0] + bq;            // qS[64][33]
            PT[2112 + r * 33 + tc]   = acc[i][1] + bk;            // kS[64][33]
            PT[4224 + r * 36 + tc]   = acc[i][2] + bv;            // vS[64][36]
        }
    }
    __syncthreads();
    // scores: thread -> row r, quarter q4 (cols q4*16..+15)
    const int r = tid >> 2, q4 = tid & 3;
    float qreg[32];
#pragma unroll
    for (int d = 0; d < 32; ++d) qreg[d] = PT[r * 33 + d] * ATTN_SCALE;
    float s[16];
#pragma unroll
    for (int j = 0; j < 16; ++j) {
        int c = q4 * 16 + j;
        float a = 0.f;
#pragma unroll
        for (int d = 0; d < 32; ++d) a += qreg[d] * PT[2112 + c * 33 + d];
        s[j] = a;
    }
    float mx = s[0];
#pragma unroll
    for (int j = 1; j < 16; ++j) mx = fmaxf(mx, s[j]);
    mx = fmaxf(mx, __shfl_xor(mx, 1));
    mx = fmaxf(mx, __shfl_xor(mx, 2));
    float sum = 0.f;
#pragma unroll
    for (int j = 0; j < 16; ++j) { s[j] = __expf(s[j] - mx); sum += s[j]; }
    sum += __shfl_xor(sum, 1);
    sum += __shfl_xor(sum, 2);
    float inv = 1.0f / sum;
    __syncthreads();   // q,k reads complete before P overlays them
#pragma unroll
    for (int j = 0; j < 16; ++j) PT[r * 66 + q4 * 16 + j] = s[j] * inv;
    __syncthreads();
    // PV: out[64][32], thread rows tr+8i, col tc
    float o[8] = {};
    for (int c = 0; c < 64; ++c) {
        float vv = PT[4224 + c * 36 + tc];
#pragma unroll
        for (int i = 0; i < 8; ++i) o[i] += PT[(tr + 8 * i) * 66 + c] * vv;
    }
#pragma unroll
    for (int i = 0; i < 8; ++i)
        oa[((size_t)win * TOK + tr + 8 * i) * CDIM + head * 32 + tc] = o[i];
}

// ---------------------------------------------------------------------------
// K5: fused GMLP with v recompute; writes product = attn .* g in-place into a_io.
// LDS: V 64x196 fp32 (p tile then v tile), U = bf16 H[64][68] + W-stage.
__launch_bounds__(256)
__global__ void gmlp_prod_kernel(const float* __restrict__ p,
                                 const float* __restrict__ w_qkv,
                                 const float* __restrict__ b_qkv,
                                 const float* __restrict__ w_g1,
                                 const float* __restrict__ b_g1,
                                 const float* __restrict__ w_g2,
                                 const float* __restrict__ b_g2,
                                 float* __restrict__ a_io) {
    __shared__ float V[64 * 196];   // 50176 B
    __shared__ float U[3744];       // 14976 B: H bf16 [0..2176), W stage [2176..3744)
    __hip_bfloat16* Hb = (__hip_bfloat16*)U;   // [64][68] ushorts = 2176 floats
    float* Wst = U + 2176;                     // up to 1568 floats
    const int tid = threadIdx.x;
    const size_t m0 = (size_t)blockIdx.x * 64;
    const int tr = tid >> 5, tc = tid & 31;
    // load p tile
    for (int i4 = tid * 4; i4 < 64 * 192; i4 += 1024) {
        float4 v = *(const float4*)&p[m0 * CDIM + i4];
        int r = i4 / 192, c = i4 - r * 192;
        *(float4*)&V[r * 196 + c] = v;
    }
    // v = p @ w_qkv[:,384:576] + b   (acc rows tr+8i, cols tc+32j)
    float vacc[8][6] = {};
    for (int k0 = 0; k0 < 192; k0 += 16) {
        __syncthreads();
        for (int i4 = tid * 4; i4 < 16 * 192; i4 += 1024) {
            int kk = i4 / 192, c = i4 - kk * 192;
            float4 w = *(const float4*)&w_qkv[(size_t)(k0 + kk) * C3 + 384 + c];
            *(float4*)&U[kk * 196 + c] = w;    // Wv stage uses U[0..3136)
        }
        __syncthreads();
#pragma unroll
        for (int k4 = 0; k4 < 16; k4 += 4) {
            float4 a[8];
#pragma unroll
            for (int i = 0; i < 8; ++i)
                a[i] = *(const float4*)&V[(tr + 8 * i) * 196 + k0 + k4];
#pragma unroll
            for (int kk = 0; kk < 4; ++kk) {
                float b[6];
#pragma unroll
                for (int j = 0; j < 6; ++j) b[j] = U[(k4 + kk) * 196 + tc + 32 * j];
#pragma unroll
                for (int i = 0; i < 8; ++i) {
                    float av = (kk == 0) ? a[i].x : (kk == 1) ? a[i].y
                             : (kk == 2) ? a[i].z : a[i].w;
#pragma unroll
                    for (int j = 0; j < 6; ++j) vacc[i][j] += av * b[j];
                }
            }
        }
    }
    __syncthreads();   // all p-tile reads done
#pragma unroll
    for (int j = 0; j < 6; ++j) {
        float bv = b_qkv[384 + tc + 32 * j];
#pragma unroll
        for (int i = 0; i < 8; ++i)
            V[(tr + 8 * i) * 196 + tc + 32 * j] = vacc[i][j] + bv;
    }
    // hidden loop: chunks of 64
    float gacc[8][6] = {};
    for (int hc = 0; hc < 12; ++hc) {
        float hacc[8][2] = {};
        for (int k0 = 0; k0 < 192; k0 += 16) {
            __syncthreads();   // also guards V writes (first iter) / prior W reads
            for (int i4 = tid * 4; i4 < 16 * 64; i4 += 1024) {
                int kk = i4 >> 6, c = i4 & 63;
                float4 w = *(const float4*)&w_g1[(size_t)(k0 + kk) * C4 + hc * 64 + c];
                *(float4*)&Wst[kk * 68 + c] = w;   // W1s [16][68]
            }
            __syncthreads();
#pragma unroll
            for (int k4 = 0; k4 < 16; k4 += 4) {
                float4 a[8];
#pragma unroll
                for (int i = 0; i < 8; ++i)
                    a[i] = *(const float4*)&V[(tr + 8 * i) * 196 + k0 + k4];
#pragma unroll
                for (int kk = 0; kk < 4; ++kk) {
                    float b0 = Wst[(k4 + kk) * 68 + tc];
                    float b1 = Wst[(k4 + kk) * 68 + tc + 32];
#pragma unroll
                    for (int i = 0; i < 8; ++i) {
                        float av = (kk == 0) ? a[i].x : (kk == 1) ? a[i].y
                                 : (kk == 2) ? a[i].z : a[i].w;
                        hacc[i][0] += av * b0;
                        hacc[i][1] += av * b1;
                    }
                }
            }
        }
        // gelu -> bf16 H
        {
            float bb0 = b_g1[hc * 64 + tc];
            float bb1 = b_g1[hc * 64 + tc + 32];
#pragma unroll
            for (int i = 0; i < 8; ++i) {
                int r = tr + 8 * i;
                float x0 = hacc[i][0] + bb0;
                float x1 = hacc[i][1] + bb1;
                Hb[r * 68 + tc]      = __float2bfloat16(0.5f * x0 * (1.0f + erff(x0 * GELU_K)));
                Hb[r * 68 + tc + 32] = __float2bfloat16(0.5f * x1 * (1.0f + erff(x1 * GELU_K)));
            }
        }
        // gemm2 accumulate: gacc += H(64x64) @ w_g2[hc*64.. , :]
        for (int ks = 0; ks < 8; ++ks) {
            __syncthreads();   // H visible; prior W1s/W2s reads done
            for (int i4 = tid * 4; i4 < 8 * 192; i4 += 1024) {
                int kk = i4 / 192, c = i4 - kk * 192;
                float4 w = *(const float4*)&w_g2[(size_t)(hc * 64 + ks * 8 + kk) * CDIM + c];
                *(float4*)&Wst[kk * 196 + c] = w;   // W2s [8][196]
            }
            __syncthreads();
#pragma unroll
            for (int kk = 0; kk < 8; ++kk) {
                int k = ks * 8 + kk;
                float hv[8];
#pragma unroll
                for (int i = 0; i < 8; ++i)
                    hv[i] = __bfloat162float(Hb[(tr + 8 * i) * 68 + k]);
                float b[6];
#pragma unroll
                for (int j = 0; j < 6; ++j) b[j] = Wst[kk * 196 + tc + 32 * j];
#pragma unroll
                for (int i = 0; i < 8; ++i)
#pragma unroll
                    for (int j = 0; j < 6; ++j) gacc[i][j] += hv[i] * b[j];
            }
        }
    }
    // product in place: a_io = a_io * (g + b_g2)
#pragma unroll
    for (int j = 0; j < 6; ++j) {
        float bg = b_g2[tc + 32 * j];
#pragma unroll
        for (int i = 0; i < 8; ++i) {
            size_t idx = (m0 + tr + 8 * i) * CDIM + tc + 32 * j;
            a_io[idx] = a_io[idx] * (gacc[i][j] + bg);
        }
    }
}

// ---------------------------------------------------------------------------
// K7: fused = product @ w_proj + b (in-place into a_io), recon loss vs p.
__launch_bounds__(256)
__global__ void proj_recon_kernel(const float* __restrict__ w_proj,
                                  const float* __restrict__ b_proj,
                                  const float* __restrict__ w_rec,
                                  const float* __restrict__ b_rec,
                                  const float* __restrict__ p,
                                  float* __restrict__ a_io,
                                  float* __restrict__ loss) {
    __shared__ float T[64 * 196];     // 50176 B (product tile, then fused tile)
    __shared__ float WT[16 * 196];    // 12544 B
    __shared__ float red[256];
    const int tid = threadIdx.x;
    const size_t m0 = (size_t)blockIdx.x * 64;
    const int tr = tid >> 5, tc = tid & 31;
    for (int i4 = tid * 4; i4 < 64 * 192; i4 += 1024) {
        float4 v = *(const float4*)&a_io[m0 * CDIM + i4];
        int r = i4 / 192, c = i4 - r * 192;
        *(float4*)&T[r * 196 + c] = v;
    }
    float facc[8][6] = {};
    for (int k0 = 0; k0 < 192; k0 += 16) {
        __syncthreads();
        for (int i4 = tid * 4; i4 < 16 * 192; i4 += 1024) {
            int kk = i4 / 192, c = i4 - kk * 192;
            float4 w = *(const float4*)&w_proj[(size_t)(k0 + kk) * CDIM + c];
            *(float4*)&WT[kk * 196 + c] = w;
        }
        __syncthreads();
#pragma unroll
        for (int k4 = 0; k4 < 16; k4 += 4) {
            float4 a[8];
#pragma unroll
            for (int i = 0; i < 8; ++i)
                a[i] = *(const float4*)&T[(tr + 8 * i) * 196 + k0 + k4];
#pragma unroll
            for (int kk = 0; kk < 4; ++kk) {
                float b[6];
#pragma unroll
                for (int j = 0; j < 6; ++j) b[j] = WT[(k4 + kk) * 196 + tc + 32 * j];
#pragma unroll
                for (int i = 0; i < 8; ++i) {
                    float av = (kk == 0) ? a[i].x : (kk == 1) ? a[i].y
                             : (kk == 2) ? a[i].z : a[i].w;
#pragma unroll
                    for (int j = 0; j < 6; ++j) facc[i][j] += av * b[j];
                }
            }
        }
    }
    __syncthreads();   // all product-tile reads complete
    // fused = facc + b_proj: overlay into T, write out to a_io
#pragma unroll
    for (int j = 0; j < 6; ++j) {
        float bp = b_proj[tc + 32 * j];
#pragma unroll
        for (int i = 0; i < 8; ++i) {
            float fv = facc[i][j] + bp;
            T[(tr + 8 * i) * 196 + tc + 32 * j] = fv;
            a_io[(m0 + tr + 8 * i) * CDIM + tc + 32 * j] = fv;
        }
    }
    // recon = fused @ w_rec + b_rec; loss += mean|recon - p| * 0.1
    float racc[8][6] = {};
    for (int k0 = 0; k0 < 192; k0 += 16) {
        __syncthreads();
        for (int i4 = tid * 4; i4 < 16 * 192; i4 += 1024) {
            int kk = i4 / 192, c = i4 - kk * 192;
            float4 w = *(const float4*)&w_rec[(size_t)(k0 + kk) * CDIM + c];
            *(float4*)&WT[kk * 196 + c] = w;
        }
        __syncthreads();
#pragma unroll
        for (int k4 = 0; k4 < 16; k4 += 4) {
            float4 a[8];
#pragma unroll
            for (int i = 0; i < 8; ++i)
                a[i] = *(const float4*)&T[(tr + 8 * i) * 196 + k0 + k4];
#pragma unroll
            for (int kk = 0; kk < 4; ++kk) {
                float b[6];
#pragma unroll
                for (int j = 0; j < 6; ++j) b[j] = WT[(k4 + kk) * 196 + tc + 32 * j];
#pragma unroll
                for (int i = 0; i < 8; ++i) {
                    float av = (kk == 0) ? a[i].x : (kk == 1) ? a[i].y
                             : (kk == 2) ? a[i].z : a[i].w;
#pragma unroll
                    for (int j = 0; j < 6; ++j) racc[i][j] += av * b[j];
                }
            }
        }
    }
    float ls = 0.f;
#pragma unroll
    for (int j = 0; j < 6; ++j) {
        float br = b_rec[tc + 32 * j];
#pragma unroll
        for (int i = 0; i < 8; ++i) {
            float rv = racc[i][j] + br;
            ls += fabsf(rv - p[(m0 + tr + 8 * i) * CDIM + tc + 32 * j]);
        }
    }
    red[tid] = ls;
    __syncthreads();
    for (int s = 128; s > 0; s >>= 1) {
        if (tid < s) red[tid] += red[tid + s];
        __syncthreads();
    }
    if (tid == 0) atomicAdd(loss, red[0] * (0.1f / (float)IMGSZ));
}

// ---------------------------------------------------------------------------
// K8: window reverse + residual.
__launch_bounds__(256)
__global__ void reverse_res_kernel(const float* __restrict__ fused,
                                   const float* __restrict__ x,
                                   float* __restrict__ out) {
    __shared__ float T[CDIM][33];
    const int tid = threadIdx.x;
    const int wt = blockIdx.x, h = blockIdx.y, b = blockIdx.z;
    const int w0 = wt * 32;
    const int l = tid & 63, jo = tid >> 6;
    for (int it = 0; it < 8; ++it) {
        int j = it * 4 + jo;
        int w = w0 + j;
        size_t token = ((size_t)(b * NWH + (h >> 3)) * NWH + (w >> 3)) * TOK
                       + ((h & 7) * 8 + (w & 7));
#pragma unroll
        for (int rep = 0; rep < 3; ++rep) {
            int c = l + rep * 64;
            T[c][j] = fused[token * CDIM + c];
        }
    }
    __syncthreads();
    const size_t rowbase = (size_t)b * CDIM * HWSZ + (size_t)h * WDIM + w0;
    for (int idx = tid; idx < CDIM * 32; idx += 256) {
        int c = idx >> 5, j = idx & 31;
        size_t gp = rowbase + (size_t)c * HWSZ + j;
        out[gp] = T[c][j] + x[gp];
    }
}

// ---------------------------------------------------------------------------
extern "C" void kernel_launch(void* const* d_in, const int* in_sizes, int n_in,
                              void* d_out, int out_size, void* d_ws, size_t ws_size,
                              hipStream_t stream) {
    const float* x      = (const float*)d_in[0];
    const float* w_pre1 = (const float*)d_in[1];
    const float* b_pre1 = (const float*)d_in[2];
    const float* w_dw   = (const float*)d_in[3];
    const float* b_dw   = (const float*)d_in[4];
    const float* ln_g   = (const float*)d_in[5];
    const float* ln_b   = (const float*)d_in[6];
    const float* w_qkv  = (const float*)d_in[7];
    const float* b_qkv  = (const float*)d_in[8];
    const float* w_proj = (const float*)d_in[9];
    const float* b_proj = (const float*)d_in[10];
    const float* w_g1   = (const float*)d_in[11];
    const float* b_g1   = (const float*)d_in[12];
    const float* w_g2   = (const float*)d_in[13];
    const float* b_g2   = (const float*)d_in[14];
    const float* w_rec  = (const float*)d_in[15];
    const float* b_rec  = (const float*)d_in[16];

    float* OutR = (float*)d_out;           // scratch (f1, then p), final output
    float* loss = OutR + (size_t)IMGSZ;
    float* A    = (float*)d_ws;            // single 147 MB region

    hipMemsetAsync(loss, 0, sizeof(float), stream);

    // K1: f1 = conv1x1(x)  -> OutR
    conv1x1_kernel<<<dim3(HWSZ / 64, CDIM / 64, BATCH), 256, 0, stream>>>(
        x, w_pre1, b_pre1, OutR);
    // K2: f2 = dwconv(f1)  -> A
    dwconv_kernel<<<IMGSZ / 256, 256, 0, stream>>>(OutR, w_dw, b_dw, A);
    // K3: p = LN+partition(f2) -> OutR
    ln_part_kernel<<<dim3(WDIM / 32, HDIM, BATCH), 256, 0, stream>>>(
        A, ln_g, ln_b, OutR);
    // K4: attn (fused qkv) -> A
    attn_fused_kernel<<<dim3(NWIN, HEADS), 256, 0, stream>>>(
        OutR, w_qkv, b_qkv, A);
    // K5: A = attn .* gmlp(v) in place (v recomputed from p)
    gmlp_prod_kernel<<<MTOK / 64, 256, 0, stream>>>(
        OutR, w_qkv, b_qkv, w_g1, b_g1, w_g2, b_g2, A);
    // K7: A = product @ w_proj + b (in place); recon loss vs p -> loss
    proj_recon_kernel<<<MTOK / 64, 256, 0, stream>>>(
        w_proj, b_proj, w_rec, b_rec, OutR, A, loss);
    // K8: out = reverse(A) + x -> OutR
    reverse_res_kernel<<<dim3(WDIM / 32, HDIM, BATCH), 256, 0, stream>>>(
        A, x, OutR);
}

// Round 3
// 3561.020 us; speedup vs baseline: 21.7281x; 21.7281x over previous
//
#include <hip/hip_runtime.h>
#include <hip/hip_bf16.h>
#include <math.h>

// Problem constants
#define BATCH 4
#define CDIM 192
#define HDIM 224
#define WDIM 224
#define HWSZ (HDIM * WDIM)            // 50176
#define NWH 28                        // 224/8
#define NWIN (BATCH * NWH * NWH)      // 3136
#define TOK 64
#define MTOK (NWIN * TOK)             // 200704
#define HEADS 6
#define C3 (3 * CDIM)                 // 576
#define C4 (4 * CDIM)                 // 768
#define IMGSZ (BATCH * CDIM * HWSZ)   // 38535168
#define ATTN_SCALE 0.17677669529663687f
#define LN_EPS 1e-6f

typedef __attribute__((ext_vector_type(8))) short bfrag;   // 8 bf16 (4 VGPRs)
typedef __attribute__((ext_vector_type(4))) float f32x4;

__device__ __forceinline__ float bf2f(unsigned short u) {
    union { unsigned int i; float f; } v; v.i = ((unsigned int)u) << 16; return v.f;
}
__device__ __forceinline__ unsigned short f2bf(float f) {
    union { unsigned int i; float f; } v; v.f = f;
    unsigned int r = (v.i + 0x7FFFu + ((v.i >> 16) & 1u)) >> 16;   // RNE
    return (unsigned short)r;
}
// exact-erf GELU via Abramowitz-Stegun 7.1.26 (|erf err| <= 1.5e-7)
__device__ __forceinline__ float gelu_erf(float x) {
    float z = fabsf(x) * 0.70710678118654752f;
    float t = __fdividef(1.0f, 1.0f + 0.3275911f * z);
    float poly = t * (0.254829592f + t * (-0.284496736f +
                 t * (1.421413741f + t * (-1.453152027f + t * 1.061405429f))));
    float erfv = 1.0f - poly * __expf(-z * z);
    erfv = (x < 0.f) ? -erfv : erfv;
    return 0.5f * x * (1.0f + erfv);
}

// ---------------------------------------------------------------------------
// Prep: transpose+convert weights to bf16 (n-major, k-contiguous) once/launch.
__launch_bounds__(256)
__global__ void prep_weights_kernel(const float* __restrict__ w_qkv,
                                    const float* __restrict__ w_g1,
                                    const float* __restrict__ w_g2,
                                    ushort* __restrict__ WvT,
                                    ushort* __restrict__ W1T,
                                    ushort* __restrict__ W2T) {
    int idx = blockIdx.x * 256 + threadIdx.x;
    if (idx < 192 * 192) {
        int n = idx / 192, k = idx % 192;
        WvT[idx] = f2bf(w_qkv[(size_t)k * C3 + 384 + n]);
    }
    if (idx < 768 * 192) {
        int n = idx / 192, k = idx % 192;
        W1T[idx] = f2bf(w_g1[(size_t)k * C4 + n]);
    }
    if (idx < 192 * 768) {
        int n = idx / 768, k = idx % 768;
        W2T[idx] = f2bf(w_g2[(size_t)k * CDIM + n]);
    }
}

// ---------------------------------------------------------------------------
// K1: 1x1 conv == per-batch GEMM (fp32)
__launch_bounds__(256)
__global__ void conv1x1_kernel(const float* __restrict__ x,
                               const float* __restrict__ w1,
                               const float* __restrict__ b1,
                               float* __restrict__ f1) {
    __shared__ __align__(16) float As[16][68];
    __shared__ __align__(16) float Bs[16][64];
    const int tid = threadIdx.x;
    const int p0 = blockIdx.x * 64;
    const int m0 = blockIdx.y * 64;
    const int b  = blockIdx.z;
    const int tm = tid >> 4, tn = tid & 15;
    const int mload = tid >> 2, kload = (tid & 3) * 4;
    const int kw = tid >> 4, nw = (tid & 15) * 4;
    float acc[4][4] = {};
    const float* xb = x + (size_t)b * CDIM * HWSZ;
    for (int k0 = 0; k0 < CDIM; k0 += 16) {
        float4 av = *(const float4*)&w1[(size_t)(m0 + mload) * CDIM + k0 + kload];
        float4 bv = *(const float4*)&xb[(size_t)(k0 + kw) * HWSZ + p0 + nw];
        __syncthreads();
        As[kload + 0][mload] = av.x;
        As[kload + 1][mload] = av.y;
        As[kload + 2][mload] = av.z;
        As[kload + 3][mload] = av.w;
        *(float4*)&Bs[kw][nw] = bv;
        __syncthreads();
#pragma unroll
        for (int kk = 0; kk < 16; ++kk) {
            float a[4], bb[4];
            *(float4*)a  = *(const float4*)&As[kk][tm * 4];
            *(float4*)bb = *(const float4*)&Bs[kk][tn * 4];
#pragma unroll
            for (int i = 0; i < 4; ++i)
#pragma unroll
                for (int j = 0; j < 4; ++j) acc[i][j] += a[i] * bb[j];
        }
    }
    float* outb = f1 + (size_t)b * CDIM * HWSZ;
#pragma unroll
    for (int i = 0; i < 4; ++i) {
        int m = m0 + tm * 4 + i;
        float bias = b1[m];
        float4 o = make_float4(acc[i][0] + bias, acc[i][1] + bias,
                               acc[i][2] + bias, acc[i][3] + bias);
        *(float4*)&outb[(size_t)m * HWSZ + p0 + tn * 4] = o;
    }
}

// ---------------------------------------------------------------------------
// K2: depthwise 3x3 SAME, NCHW.
__launch_bounds__(256)
__global__ void dwconv_kernel(const float* __restrict__ f1,
                              const float* __restrict__ w_dw,
                              const float* __restrict__ b_dw,
                              float* __restrict__ f2) {
    unsigned int idx = blockIdx.x * 256u + threadIdx.x;
    int w = idx % WDIM;
    unsigned int r = idx / WDIM;
    int h = r % HDIM;
    unsigned int bc = r / HDIM;
    int c = bc % CDIM;
    const float* base = f1 + (size_t)bc * HWSZ;
    const float* wd = w_dw + c * 9;
    float acc = b_dw[c];
#pragma unroll
    for (int ky = 0; ky < 3; ++ky) {
        int hy = h + ky - 1;
        if (hy < 0 || hy >= HDIM) continue;
#pragma unroll
        for (int kx = 0; kx < 3; ++kx) {
            int wx = w + kx - 1;
            if (wx < 0 || wx >= WDIM) continue;
            acc += base[hy * WDIM + wx] * wd[ky * 3 + kx];
        }
    }
    f2[idx] = acc;
}

// ---------------------------------------------------------------------------
// K3: LayerNorm over C + window partition -> token-major pb[M][192] (bf16).
__launch_bounds__(256)
__global__ void ln_part_kernel(const float* __restrict__ f2,
                               const float* __restrict__ ln_g,
                               const float* __restrict__ ln_b,
                               ushort* __restrict__ pb) {
    __shared__ float T[CDIM][33];
    __shared__ float Rs[8][32], Rs2[8][32];
    __shared__ float Mu[32], Rsig[32];
    const int tid = threadIdx.x;
    const int wt = blockIdx.x, h = blockIdx.y, b = blockIdx.z;
    const int w0 = wt * 32;
    const size_t rowbase = (size_t)b * CDIM * HWSZ + (size_t)h * WDIM + w0;
    for (int idx = tid; idx < CDIM * 32; idx += 256) {
        int c = idx >> 5, j = idx & 31;
        T[c][j] = f2[rowbase + (size_t)c * HWSZ + j];
    }
    __syncthreads();
    {
        int j = tid & 31, q = tid >> 5;
        float s = 0.f, s2 = 0.f;
#pragma unroll
        for (int i = 0; i < 24; ++i) {
            float v = T[q * 24 + i][j];
            s += v; s2 += v * v;
        }
        Rs[q][j] = s; Rs2[q][j] = s2;
    }
    __syncthreads();
    if (tid < 32) {
        float s = 0.f, s2 = 0.f;
#pragma unroll
        for (int q = 0; q < 8; ++q) { s += Rs[q][tid]; s2 += Rs2[q][tid]; }
        float mu = s * (1.0f / CDIM);
        float var = s2 * (1.0f / CDIM) - mu * mu;
        Mu[tid] = mu;
        Rsig[tid] = rsqrtf(var + LN_EPS);
    }
    __syncthreads();
    const int l = tid & 63;
    const int jo = tid >> 6;
    for (int it = 0; it < 8; ++it) {
        int j = it * 4 + jo;
        int w = w0 + j;
        size_t token = ((size_t)(b * NWH + (h >> 3)) * NWH + (w >> 3)) * TOK
                       + ((h & 7) * 8 + (w & 7));
        float mu = Mu[j], rs = Rsig[j];
#pragma unroll
        for (int rep = 0; rep < 3; ++rep) {
            int c = l + rep * 64;
            pb[token * CDIM + c] = f2bf((T[c][j] - mu) * rs * ln_g[c] + ln_b[c]);
        }
    }
}

// ---------------------------------------------------------------------------
// K4: fused qkv + attention per (window, head). 256 threads. fp32 math,
// bf16 p input.
__launch_bounds__(256)
__global__ void attn_fused_kernel(const ushort* __restrict__ pb,
                                  const float* __restrict__ w_qkv,
                                  const float* __restrict__ b_qkv,
                                  float* __restrict__ oa) {
    __shared__ float PT[64 * 196];   // 50176 B
    __shared__ float WS[16 * 100];   // 6400 B
    const int tid = threadIdx.x;
    const int win = blockIdx.x, head = blockIdx.y;
    const size_t pbase = (size_t)win * TOK * CDIM;
    for (int i8 = tid * 8; i8 < 64 * 192; i8 += 2048) {
        uint4 raw = *(const uint4*)&pb[pbase + i8];
        int r = i8 / 192, c = i8 % 192;
        float* dst = &PT[r * 196 + c];
        const ushort* u = (const ushort*)&raw;
#pragma unroll
        for (int j = 0; j < 8; ++j) dst[j] = bf2f(u[j]);
    }
    const int tr = tid >> 5, tc = tid & 31;
    float acc[8][3] = {};
    for (int k0 = 0; k0 < 192; k0 += 16) {
        __syncthreads();
        for (int idx = tid; idx < 16 * 96; idx += 256) {
            int kk = idx / 96, j = idx - kk * 96;
            int col = (j < 32) ? head * 32 + j
                    : (j < 64) ? 192 + head * 32 + (j - 32)
                               : 384 + head * 32 + (j - 64);
            WS[kk * 100 + j] = w_qkv[(size_t)(k0 + kk) * C3 + col];
        }
        __syncthreads();
#pragma unroll
        for (int k4 = 0; k4 < 16; k4 += 4) {
            float4 a[8];
#pragma unroll
            for (int i = 0; i < 8; ++i)
                a[i] = *(const float4*)&PT[(tr + 8 * i) * 196 + k0 + k4];
#pragma unroll
            for (int kk = 0; kk < 4; ++kk) {
                float b0 = WS[(k4 + kk) * 100 + tc];
                float b1 = WS[(k4 + kk) * 100 + tc + 32];
                float b2 = WS[(k4 + kk) * 100 + tc + 64];
#pragma unroll
                for (int i = 0; i < 8; ++i) {
                    float av = (kk == 0) ? a[i].x : (kk == 1) ? a[i].y
                             : (kk == 2) ? a[i].z : a[i].w;
                    acc[i][0] += av * b0;
                    acc[i][1] += av * b1;
                    acc[i][2] += av * b2;
                }
            }
        }
    }
    __syncthreads();
    {
        float bq = b_qkv[head * 32 + tc];
        float bk = b_qkv[192 + head * 32 + tc];
        float bv = b_qkv[384 + head * 32 + tc];
#pragma unroll
        for (int i = 0; i < 8; ++i) {
            int r = tr + 8 * i;
            PT[r * 33 + tc]          = acc[i][0] + bq;
            PT[2112 + r * 33 + tc]   = acc[i][1] + bk;
            PT[4224 + r * 36 + tc]   = acc[i][2] + bv;
        }
    }
    __syncthreads();
    const int r = tid >> 2, q4 = tid & 3;
    float qreg[32];
#pragma unroll
    for (int d = 0; d < 32; ++d) qreg[d] = PT[r * 33 + d] * ATTN_SCALE;
    float s[16];
#pragma unroll
    for (int j = 0; j < 16; ++j) {
        int c = q4 * 16 + j;
        float a = 0.f;
#pragma unroll
        for (int d = 0; d < 32; ++d) a += qreg[d] * PT[2112 + c * 33 + d];
        s[j] = a;
    }
    float mx = s[0];
#pragma unroll
    for (int j = 1; j < 16; ++j) mx = fmaxf(mx, s[j]);
    mx = fmaxf(mx, __shfl_xor(mx, 1));
    mx = fmaxf(mx, __shfl_xor(mx, 2));
    float sum = 0.f;
#pragma unroll
    for (int j = 0; j < 16; ++j) { s[j] = __expf(s[j] - mx); sum += s[j]; }
    sum += __shfl_xor(sum, 1);
    sum += __shfl_xor(sum, 2);
    float inv = 1.0f / sum;
    __syncthreads();
#pragma unroll
    for (int j = 0; j < 16; ++j) PT[r * 66 + q4 * 16 + j] = s[j] * inv;
    __syncthreads();
    const int tr2 = tid >> 5, tc2 = tid & 31;
    float o[8] = {};
    for (int c = 0; c < 64; ++c) {
        float vv = PT[4224 + c * 36 + tc2];
#pragma unroll
        for (int i = 0; i < 8; ++i) o[i] += PT[(tr2 + 8 * i) * 66 + c] * vv;
    }
#pragma unroll
    for (int i = 0; i < 8; ++i)
        oa[((size_t)win * TOK + tr2 + 8 * i) * CDIM + head * 32 + tc2] = o[i];
}

// ---------------------------------------------------------------------------
// K5: MFMA GMLP. Block = 64 tokens, 4 waves. v = p@Wv+b (MFMA, K=192);
// hidden in 12 chunks of 64: GEMM1 -> gelu(bf16 H in LDS) -> GEMM2 acc.
// Epilogue: a_io *= (g + b_g2)  (product with attention output, in place).
__launch_bounds__(256)
__global__ void gmlp_mfma_kernel(const ushort* __restrict__ pb,
                                 const ushort* __restrict__ WvT,
                                 const float* __restrict__ b_qkv,
                                 const ushort* __restrict__ W1T,
                                 const float* __restrict__ b_g1,
                                 const ushort* __restrict__ W2T,
                                 const float* __restrict__ b_g2,
                                 float* __restrict__ a_io) {
    __shared__ ushort Ab[64 * 200];   // 25600 B: p tile then V tile (bf16)
    __shared__ ushort Wb[192 * 72];   // 27648 B: weight chunks (two layouts)
    __shared__ ushort Hb[64 * 72];    // 9216 B: gelu hidden chunk (bf16)
    const int tid = threadIdx.x;
    const int lane = tid & 63, wave = tid >> 6;
    const int quad = lane >> 4, l16 = lane & 15;
    const int m0 = wave * 16;
    const size_t tok0 = (size_t)blockIdx.x * 64;

    // stage p tile (bf16 passthrough), 16B chunks
    for (int idx = tid * 8; idx < 64 * 192; idx += 2048) {
        int r = idx / 192, c = idx % 192;
        *(uint4*)&Ab[r * 200 + c] = *(const uint4*)&pb[(tok0 + r) * 192 + c];
    }

    // ---- v-GEMM: 64x192, K=192 ----
    f32x4 vacc[12];
#pragma unroll
    for (int i = 0; i < 12; ++i) vacc[i] = (f32x4){0.f, 0.f, 0.f, 0.f};
#pragma unroll
    for (int nc = 0; nc < 3; ++nc) {
        __syncthreads();
        for (int idx = tid * 8; idx < 64 * 192; idx += 2048) {
            int r = idx / 192, c = idx % 192;
            *(uint4*)&Wb[r * 200 + c] = *(const uint4*)&WvT[(size_t)(nc * 64 + r) * 192 + c];
        }
        __syncthreads();
#pragma unroll
        for (int kk = 0; kk < 6; ++kk) {
            bfrag a = *(const bfrag*)&Ab[(m0 + l16) * 200 + kk * 32 + quad * 8];
#pragma unroll
            for (int t = 0; t < 4; ++t) {
                bfrag b = *(const bfrag*)&Wb[(t * 16 + l16) * 200 + kk * 32 + quad * 8];
                vacc[nc * 4 + t] = __builtin_amdgcn_mfma_f32_16x16x32_bf16(
                    a, b, vacc[nc * 4 + t], 0, 0, 0);
            }
        }
    }
    // write V (bf16) into this wave's own rows of Ab
#pragma unroll
    for (int i = 0; i < 12; ++i) {
        int n = i * 16 + l16;
        float bias = b_qkv[384 + n];
#pragma unroll
        for (int reg = 0; reg < 4; ++reg) {
            int r = m0 + quad * 4 + reg;
            Ab[r * 200 + n] = f2bf(vacc[i][reg] + bias);
        }
    }

    // ---- hidden loop ----
    f32x4 acc2[12];
#pragma unroll
    for (int i = 0; i < 12; ++i) acc2[i] = (f32x4){0.f, 0.f, 0.f, 0.f};
    for (int hc = 0; hc < 12; ++hc) {
        __syncthreads();   // prior Wb reads done (also covers Ab staging/V writes)
        for (int idx = tid * 8; idx < 64 * 192; idx += 2048) {
            int r = idx / 192, c = idx % 192;
            *(uint4*)&Wb[r * 200 + c] =
                *(const uint4*)&W1T[((size_t)hc * 64 + r) * 192 + c];
        }
        __syncthreads();
        // GEMM1: H chunk 64x64, K=192
        f32x4 acc1[4];
#pragma unroll
        for (int t = 0; t < 4; ++t) acc1[t] = (f32x4){0.f, 0.f, 0.f, 0.f};
#pragma unroll
        for (int kk = 0; kk < 6; ++kk) {
            bfrag a = *(const bfrag*)&Ab[(m0 + l16) * 200 + kk * 32 + quad * 8];
#pragma unroll
            for (int t = 0; t < 4; ++t) {
                bfrag b = *(const bfrag*)&Wb[(t * 16 + l16) * 200 + kk * 32 + quad * 8];
                acc1[t] = __builtin_amdgcn_mfma_f32_16x16x32_bf16(a, b, acc1[t], 0, 0, 0);
            }
        }
        // gelu -> Hb (own-wave rows)
#pragma unroll
        for (int t = 0; t < 4; ++t) {
            int n = t * 16 + l16;
            float bb = b_g1[hc * 64 + n];
#pragma unroll
            for (int reg = 0; reg < 4; ++reg) {
                float xv = acc1[t][reg] + bb;
                Hb[(m0 + quad * 4 + reg) * 72 + n] = f2bf(gelu_erf(xv));
            }
        }
        __syncthreads();   // W1 reads done before W2 overwrite
        for (int idx = tid * 8; idx < 192 * 64; idx += 2048) {
            int r = idx / 64, c = idx % 64;
            *(uint4*)&Wb[r * 72 + c] =
                *(const uint4*)&W2T[(size_t)r * 768 + hc * 64 + c];
        }
        __syncthreads();
        // GEMM2 accumulate: 64x192, K=64
#pragma unroll
        for (int kk = 0; kk < 2; ++kk) {
            bfrag a = *(const bfrag*)&Hb[(m0 + l16) * 72 + kk * 32 + quad * 8];
#pragma unroll
            for (int t = 0; t < 12; ++t) {
                bfrag b = *(const bfrag*)&Wb[(t * 16 + l16) * 72 + kk * 32 + quad * 8];
                acc2[t] = __builtin_amdgcn_mfma_f32_16x16x32_bf16(a, b, acc2[t], 0, 0, 0);
            }
        }
    }
    // epilogue: product with attention output, in place
#pragma unroll
    for (int t = 0; t < 12; ++t) {
        int c = t * 16 + l16;
        float bg = b_g2[c];
#pragma unroll
        for (int reg = 0; reg < 4; ++reg) {
            size_t idx = (tok0 + m0 + quad * 4 + reg) * CDIM + c;
            a_io[idx] *= (acc2[t][reg] + bg);
        }
    }
}

// ---------------------------------------------------------------------------
// K7: fused = product @ w_proj + b (in-place), recon loss vs pb (bf16 target).
__launch_bounds__(256)
__global__ void proj_recon_kernel(const float* __restrict__ w_proj,
                                  const float* __restrict__ b_proj,
                                  const float* __restrict__ w_rec,
                                  const float* __restrict__ b_rec,
                                  const ushort* __restrict__ pb,
                                  float* __restrict__ a_io,
                                  float* __restrict__ loss) {
    __shared__ float T[64 * 196];
    __shared__ float WT[16 * 196];
    __shared__ float red[256];
    const int tid = threadIdx.x;
    const size_t m0 = (size_t)blockIdx.x * 64;
    const int tr = tid >> 5, tc = tid & 31;
    for (int i4 = tid * 4; i4 < 64 * 192; i4 += 1024) {
        float4 v = *(const float4*)&a_io[m0 * CDIM + i4];
        int r = i4 / 192, c = i4 - r * 192;
        *(float4*)&T[r * 196 + c] = v;
    }
    float facc[8][6] = {};
    for (int k0 = 0; k0 < 192; k0 += 16) {
        __syncthreads();
        for (int i4 = tid * 4; i4 < 16 * 192; i4 += 1024) {
            int kk = i4 / 192, c = i4 - kk * 192;
            float4 w = *(const float4*)&w_proj[(size_t)(k0 + kk) * CDIM + c];
            *(float4*)&WT[kk * 196 + c] = w;
        }
        __syncthreads();
#pragma unroll
        for (int k4 = 0; k4 < 16; k4 += 4) {
            float4 a[8];
#pragma unroll
            for (int i = 0; i < 8; ++i)
                a[i] = *(const float4*)&T[(tr + 8 * i) * 196 + k0 + k4];
#pragma unroll
            for (int kk = 0; kk < 4; ++kk) {
                float b[6];
#pragma unroll
                for (int j = 0; j < 6; ++j) b[j] = WT[(k4 + kk) * 196 + tc + 32 * j];
#pragma unroll
                for (int i = 0; i < 8; ++i) {
                    float av = (kk == 0) ? a[i].x : (kk == 1) ? a[i].y
                             : (kk == 2) ? a[i].z : a[i].w;
#pragma unroll
                    for (int j = 0; j < 6; ++j) facc[i][j] += av * b[j];
                }
            }
        }
    }
    __syncthreads();
#pragma unroll
    for (int j = 0; j < 6; ++j) {
        float bp = b_proj[tc + 32 * j];
#pragma unroll
        for (int i = 0; i < 8; ++i) {
            float fv = facc[i][j] + bp;
            T[(tr + 8 * i) * 196 + tc + 32 * j] = fv;
            a_io[(m0 + tr + 8 * i) * CDIM + tc + 32 * j] = fv;
        }
    }
    float racc[8][6] = {};
    for (int k0 = 0; k0 < 192; k0 += 16) {
        __syncthreads();
        for (int i4 = tid * 4; i4 < 16 * 192; i4 += 1024) {
            int kk = i4 / 192, c = i4 - kk * 192;
            float4 w = *(const float4*)&w_rec[(size_t)(k0 + kk) * CDIM + c];
            *(float4*)&WT[kk * 196 + c] = w;
        }
        __syncthreads();
#pragma unroll
        for (int k4 = 0; k4 < 16; k4 += 4) {
            float4 a[8];
#pragma unroll
            for (int i = 0; i < 8; ++i)
                a[i] = *(const float4*)&T[(tr + 8 * i) * 196 + k0 + k4];
#pragma unroll
            for (int kk = 0; kk < 4; ++kk) {
                float b[6];
#pragma unroll
                for (int j = 0; j < 6; ++j) b[j] = WT[(k4 + kk) * 196 + tc + 32 * j];
#pragma unroll
                for (int i = 0; i < 8; ++i) {
                    float av = (kk == 0) ? a[i].x : (kk == 1) ? a[i].y
                             : (kk == 2) ? a[i].z : a[i].w;
#pragma unroll
                    for (int j = 0; j < 6; ++j) racc[i][j] += av * b[j];
                }
            }
        }
    }
    float ls = 0.f;
#pragma unroll
    for (int j = 0; j < 6; ++j) {
        float br = b_rec[tc + 32 * j];
#pragma unroll
        for (int i = 0; i < 8; ++i) {
            float rv = racc[i][j] + br;
            ls += fabsf(rv - bf2f(pb[(m0 + tr + 8 * i) * CDIM + tc + 32 * j]));
        }
    }
    red[tid] = ls;
    __syncthreads();
    for (int s = 128; s > 0; s >>= 1) {
        if (tid < s) red[tid] += red[tid + s];
        __syncthreads();
    }
    if (tid == 0) atomicAdd(loss, red[0] * (0.1f / (float)IMGSZ));
}

// ---------------------------------------------------------------------------
// K8: window reverse + residual.
__launch_bounds__(256)
__global__ void reverse_res_kernel(const float* __restrict__ fused,
                                   const float* __restrict__ x,
                                   float* __restrict__ out) {
    __shared__ float T[CDIM][33];
    const int tid = threadIdx.x;
    const int wt = blockIdx.x, h = blockIdx.y, b = blockIdx.z;
    const int w0 = wt * 32;
    const int l = tid & 63, jo = tid >> 6;
    for (int it = 0; it < 8; ++it) {
        int j = it * 4 + jo;
        int w = w0 + j;
        size_t token = ((size_t)(b * NWH + (h >> 3)) * NWH + (w >> 3)) * TOK
                       + ((h & 7) * 8 + (w & 7));
#pragma unroll
        for (int rep = 0; rep < 3; ++rep) {
            int c = l + rep * 64;
            T[c][j] = fused[token * CDIM + c];
        }
    }
    __syncthreads();
    const size_t rowbase = (size_t)b * CDIM * HWSZ + (size_t)h * WDIM + w0;
    for (int idx = tid; idx < CDIM * 32; idx += 256) {
        int c = idx >> 5, j = idx & 31;
        size_t gp = rowbase + (size_t)c * HWSZ + j;
        out[gp] = T[c][j] + x[gp];
    }
}

// ---------------------------------------------------------------------------
extern "C" void kernel_launch(void* const* d_in, const int* in_sizes, int n_in,
                              void* d_out, int out_size, void* d_ws, size_t ws_size,
                              hipStream_t stream) {
    const float* x      = (const float*)d_in[0];
    const float* w_pre1 = (const float*)d_in[1];
    const float* b_pre1 = (const float*)d_in[2];
    const float* w_dw   = (const float*)d_in[3];
    const float* b_dw   = (const float*)d_in[4];
    const float* ln_g   = (const float*)d_in[5];
    const float* ln_b   = (const float*)d_in[6];
    const float* w_qkv  = (const float*)d_in[7];
    const float* b_qkv  = (const float*)d_in[8];
    const float* w_proj = (const float*)d_in[9];
    const float* b_proj = (const float*)d_in[10];
    const float* w_g1   = (const float*)d_in[11];
    const float* b_g1   = (const float*)d_in[12];
    const float* w_g2   = (const float*)d_in[13];
    const float* b_g2   = (const float*)d_in[14];
    const float* w_rec  = (const float*)d_in[15];
    const float* b_rec  = (const float*)d_in[16];

    float* OutR = (float*)d_out;
    float* loss = OutR + (size_t)IMGSZ;
    float* A    = (float*)d_ws;            // 154 MB fp32 region

    // d_out layout during pipeline (front->back):
    //  [f1 fp32 full]  ->  [pb bf16 77MB | bf16 weights ~0.7MB | free]
    //  final: out fp32 full + loss scalar
    ushort* pb  = (ushort*)d_out;                  // MTOK*192 bf16
    ushort* WvT = pb  + (size_t)MTOK * CDIM;       // 192x192 (n-major, k-contig)
    ushort* W1T = WvT + 192 * 192;                 // 768x192
    ushort* W2T = W1T + 768 * 192;                 // 192x768

    hipMemsetAsync(loss, 0, sizeof(float), stream);

    // K1: f1 = conv1x1(x) -> d_out (fp32)
    conv1x1_kernel<<<dim3(HWSZ / 64, CDIM / 64, BATCH), 256, 0, stream>>>(
        x, w_pre1, b_pre1, OutR);
    // K2: f2 = dwconv(f1) -> A
    dwconv_kernel<<<IMGSZ / 256, 256, 0, stream>>>(OutR, w_dw, b_dw, A);
    // prep bf16 weights (after f1 is dead)
    prep_weights_kernel<<<(768 * 192 + 255) / 256, 256, 0, stream>>>(
        w_qkv, w_g1, w_g2, WvT, W1T, W2T);
    // K3: pb = LN+partition(f2) -> d_out front (bf16)
    ln_part_kernel<<<dim3(WDIM / 32, HDIM, BATCH), 256, 0, stream>>>(
        A, ln_g, ln_b, pb);
    // K4: attn (fused qkv) -> A
    attn_fused_kernel<<<dim3(NWIN, HEADS), 256, 0, stream>>>(
        pb, w_qkv, b_qkv, A);
    // K5: A = attn .* gmlp(v) in place (MFMA)
    gmlp_mfma_kernel<<<MTOK / 64, 256, 0, stream>>>(
        pb, WvT, b_qkv, W1T, b_g1, W2T, b_g2, A);
    // K7: A = product @ w_proj + b (in place); recon loss vs pb
    proj_recon_kernel<<<MTOK / 64, 256, 0, stream>>>(
        w_proj, b_proj, w_rec, b_rec, pb, A, loss);
    // K8: out = reverse(A) + x -> d_out
    reverse_res_kernel<<<dim3(WDIM / 32, HDIM, BATCH), 256, 0, stream>>>(
        A, x, OutR);
}